// Round 10
// baseline (283.886 us; speedup 1.0000x reference)
//
#include <hip/hip_runtime.h>

#define N_NODES 50000
#define N_EDGES 800000
#define D_IN    512
#define D_OUT   128
#define N_SUP   2
#define N_COLS  (N_SUP * D_OUT)            // 256 combined output cols
#define NB_S    782                        // 64-row buckets per support
#define NB      (N_SUP * NB_S)             // 1564 buckets
#define CAPF    1280                       // bucket capacity (mean 1023 + 8 sigma)
#define CHUNK   3125                       // 800000 = 256 * 3125 exactly
#define TILE_R  16
#define NTILES  (N_NODES / TILE_R)         // 3125 exactly
#define GGRID   256                        // persistent gemm blocks

typedef __attribute__((ext_vector_type(8))) __bf16 bf16x8;
typedef __attribute__((ext_vector_type(4))) float  f32x4;

// ---------------------------------------------------------------------------
// K1: GEMM pre[s] = bf16(x) @ bf16(W[s]).
// Round-9 gemm_v2 + three changes:
//  (a) W converted fp32->bf16 IN-WAVE (256 L2-hot scalar loads, once) —
//      deletes the convert_w dispatch + wt2 buffer.
//  (b) LDS double-buffer As -> ONE barrier per tile (was 2).
//  (c) 2-tile-deep A register prefetch (f0/f1, named/unrolled, no dyn idx).
// Block 0 also zeroes gcursor (stream-ordered before scatter_coarse).
// ---------------------------------------------------------------------------
__global__ __launch_bounds__(512, 2) void gemm_bf16_v3(const float* __restrict__ x,
                                                       const float* __restrict__ w,
                                                       __bf16* __restrict__ pre,
                                                       int* __restrict__ gcursor) {
    __shared__ __align__(16) __bf16 As[2][TILE_R * 64 * 8];   // 2 x 16 KB

    const int t    = threadIdx.x;
    const int lane = t & 63;
    const int wv   = t >> 6;            // wave 0..7 -> cols [wv*32, wv*32+32)
    const int l15  = lane & 15;
    const int quad = lane >> 4;

    if (blockIdx.x == 0)
        for (int i = t; i < NB; i += 512) gcursor[i] = 0;

    // ---- B fragments straight from fp32 kernels (L2-hot after block 0) ----
    // B0[kb][j] = w[sb][(kb*4+quad)*8 + j][np]; B1 at np+16.  [== convert_w∘load]
    const int n  = wv * 32 + l15;       // global col 0..255
    const int sb = n >> 7;
    const int np = n & 127;
    bf16x8 B0[16], B1[16];
#pragma unroll
    for (int kb = 0; kb < 16; ++kb) {
        const float* wp = w + ((size_t)sb * D_IN + (kb * 4 + quad) * 8) * D_OUT + np;
#pragma unroll
        for (int j = 0; j < 8; ++j) {
            B0[kb][j] = (__bf16)wp[(size_t)j * D_OUT];
            B1[kb][j] = (__bf16)wp[(size_t)j * D_OUT + 16];
        }
    }

    const int s_out = wv >> 2;
    const int cp0   = (wv & 3) * 32 + l15;

    const int srow = t >> 5;            // staging row 0..15
    const int sc0  = (t & 31) * 2;      // chunk pair
    const int swz  = srow & 7;

    int tile = blockIdx.x;
    float4 a0, a1, a2, a3;              // tile t   (in flight)
    float4 b0, b1, b2, b3;              // tile t+G (in flight)
    {
        const float* src = x + ((size_t)tile * TILE_R + srow) * D_IN + sc0 * 8;
        a0 = ((const float4*)src)[0];
        a1 = ((const float4*)src)[1];
        a2 = ((const float4*)src)[2];
        a3 = ((const float4*)src)[3];
    }
    if (tile + GGRID < NTILES) {
        const float* src = x + ((size_t)(tile + GGRID) * TILE_R + srow) * D_IN + sc0 * 8;
        b0 = ((const float4*)src)[0];
        b1 = ((const float4*)src)[1];
        b2 = ((const float4*)src)[2];
        b3 = ((const float4*)src)[3];
    }

    int nb = 0;
    while (tile < NTILES) {
        // convert in-flight tile, stage into buffer nb
        bf16x8 lo, hi;
        lo[0] = (__bf16)a0.x; lo[1] = (__bf16)a0.y; lo[2] = (__bf16)a0.z; lo[3] = (__bf16)a0.w;
        lo[4] = (__bf16)a1.x; lo[5] = (__bf16)a1.y; lo[6] = (__bf16)a1.z; lo[7] = (__bf16)a1.w;
        hi[0] = (__bf16)a2.x; hi[1] = (__bf16)a2.y; hi[2] = (__bf16)a2.z; hi[3] = (__bf16)a2.w;
        hi[4] = (__bf16)a3.x; hi[5] = (__bf16)a3.y; hi[6] = (__bf16)a3.z; hi[7] = (__bf16)a3.w;
        *(bf16x8*)&As[nb][((size_t)srow * 64 + (sc0       ^ swz)) * 8] = lo;
        *(bf16x8*)&As[nb][((size_t)srow * 64 + ((sc0 + 1) ^ swz)) * 8] = hi;

        // rotate the register pipeline, issue load for tile+2G
        a0 = b0; a1 = b1; a2 = b2; a3 = b3;
        if (tile + 2 * GGRID < NTILES) {
            const float* src = x + ((size_t)(tile + 2 * GGRID) * TILE_R + srow) * D_IN + sc0 * 8;
            b0 = ((const float4*)src)[0];
            b1 = ((const float4*)src)[1];
            b2 = ((const float4*)src)[2];
            b3 = ((const float4*)src)[3];
        }

        __syncthreads();                // writes to As[nb] visible; As[nb^1] free

        f32x4 acc0 = (f32x4)0.f, acc1 = (f32x4)0.f;
#pragma unroll
        for (int kb = 0; kb < 16; ++kb) {
            const int c = (kb * 4 + quad) ^ (l15 & 7);
            bf16x8 a = *(const bf16x8*)&As[nb][((size_t)l15 * 64 + c) * 8];
            acc0 = __builtin_amdgcn_mfma_f32_16x16x32_bf16(a, B0[kb], acc0, 0, 0, 0);
            acc1 = __builtin_amdgcn_mfma_f32_16x16x32_bf16(a, B1[kb], acc1, 0, 0, 0);
        }

        // C layout: col = lane&15, row = quad*4 + r  [m89-verified]
        __bf16* dst = pre + ((size_t)s_out * N_NODES + (size_t)tile * TILE_R + quad * 4) * D_OUT + cp0;
#pragma unroll
        for (int r = 0; r < 4; ++r) {
            dst[(size_t)r * D_OUT]      = (__bf16)acc0[r];
            dst[(size_t)r * D_OUT + 16] = (__bf16)acc1[r];
        }

        tile += GGRID;
        nb ^= 1;
    }
}

// ---------------------------------------------------------------------------
// K2: coarse scatter — counting sort of one 3125-edge chunk into 64-row
// buckets (782/support). LDS sort + linear coalesced global write.
// Payload: (val_bits, r<<16 | col).  (unchanged from round 9)
// ---------------------------------------------------------------------------
__global__ __launch_bounds__(512) void scatter_coarse(const float* __restrict__ adj_vals,
                                                      const int* __restrict__ adj_rows,
                                                      const int* __restrict__ adj_cols,
                                                      int* __restrict__ gcursor,
                                                      uint2* __restrict__ coarse) {
    __shared__ int hist[NB_S];
    __shared__ int excl[NB_S];
    __shared__ int lbase[NB_S];
    __shared__ int rankc[NB_S];
    __shared__ int sc[1024];
    __shared__ uint2 buf[CHUNK];                    // 25000 B

    const int bid = blockIdx.x;
    const int s   = bid >> 8;                       // support
    const int ch  = bid & 255;                      // chunk 0..255
    const int t   = threadIdx.x;

    for (int b = t; b < NB_S; b += 512) { hist[b] = 0; rankc[b] = 0; }
    __syncthreads();

    const int e0 = ch * CHUNK;
    int   rr[7]; int cc[7]; float vv[7];
#pragma unroll
    for (int i = 0; i < 7; ++i) {
        const int idx = i * 512 + t;
        if (idx < CHUNK) {
            const size_t src = (size_t)s * N_EDGES + e0 + idx;
            rr[i] = adj_rows[src];
            cc[i] = adj_cols[src];
            vv[i] = adj_vals[src];
            atomicAdd(&hist[rr[i] >> 6], 1);
        } else {
            rr[i] = -1; cc[i] = 0; vv[i] = 0.f;
        }
    }
    __syncthreads();

    // 1024-wide Hillis-Steele scan, 512 threads x 2 elements
    sc[t]       = (t       < NB_S) ? hist[t]       : 0;
    sc[t + 512] = (t + 512 < NB_S) ? hist[t + 512] : 0;
    __syncthreads();
    for (int off = 1; off < 1024; off <<= 1) {
        const int a0 = (t >= off) ? sc[t - off] : 0;
        const int a1 = sc[t + 512 - off];
        __syncthreads();
        sc[t]       += a0;
        sc[t + 512] += a1;
        __syncthreads();
    }
#pragma unroll
    for (int h = 0; h < 2; ++h) {
        const int b = t + h * 512;
        if (b < NB_S) {
            excl[b]  = sc[b] - hist[b];
            lbase[b] = hist[b] ? atomicAdd(&gcursor[s * NB_S + b], hist[b]) : 0;
        }
    }
    __syncthreads();

#pragma unroll
    for (int i = 0; i < 7; ++i) {
        if (rr[i] >= 0) {
            const int b   = rr[i] >> 6;
            const int pos = excl[b] + atomicAdd(&rankc[b], 1);
            buf[pos] = make_uint2(__float_as_uint(vv[i]),
                                  ((unsigned)rr[i] << 16) | (unsigned)cc[i]);
        }
    }
    __syncthreads();

    for (int i = t; i < CHUNK; i += 512) {
        const uint2 ed = buf[i];
        const int b   = (int)(ed.y >> 22);          // r>>6
        const int dst = lbase[b] + (i - excl[b]);
        if (dst < CAPF)                             // statistically impossible overflow guard
            coarse[(size_t)(s * NB_S + b) * CAPF + dst] = ed;
    }
}

// ---------------------------------------------------------------------------
// K3: fine sort + gather, merged. (unchanged from round 9 — proven 66 us)
// ---------------------------------------------------------------------------
__global__ __launch_bounds__(512) void fine_gather(const uint2* __restrict__ coarse,
                                                   const int* __restrict__ gcursor,
                                                   const uint4* __restrict__ pre_q,
                                                   const float* __restrict__ bias,
                                                   float* __restrict__ out) {
    __shared__ uint2 buf[2 * CAPF];                 // 20480 B (row-sorted, 2 supports)
    __shared__ int rex[2][64];
    __shared__ int rcnt[2][64];
    __shared__ int rh[64];
    __shared__ int rc[64];
    __shared__ int sd[64];

    const int bk = blockIdx.x;                      // 0..781
    const int t  = threadIdx.x;

    // ---- sort both supports' buckets by local row ----
#pragma unroll
    for (int s = 0; s < N_SUP; ++s) {
        if (t < 64) { rh[t] = 0; rc[t] = 0; }
        __syncthreads();

        const int bkt  = s * NB_S + bk;
        const size_t b0 = (size_t)bkt * CAPF;
        const int cnt  = min(gcursor[bkt], CAPF);

        uint2 ev0, ev1, ev2;                        // 3*512 = 1536 >= CAPF
        ev0 = make_uint2(0u, 0u); ev1 = ev0; ev2 = ev0;
        if (t < cnt)        { ev0 = coarse[b0 + t];        atomicAdd(&rh[(ev0.y >> 16) & 63], 1); }
        if (t + 512 < cnt)  { ev1 = coarse[b0 + t + 512];  atomicAdd(&rh[(ev1.y >> 16) & 63], 1); }
        if (t + 1024 < cnt) { ev2 = coarse[b0 + t + 1024]; atomicAdd(&rh[(ev2.y >> 16) & 63], 1); }
        __syncthreads();

        if (t < 64) sd[t] = rh[t];
        __syncthreads();
        for (int off = 1; off < 64; off <<= 1) {
            const int a = (t < 64 && t >= off) ? sd[t - off] : 0;
            __syncthreads();
            if (t < 64) sd[t] += a;
            __syncthreads();
        }
        if (t < 64) {
            rex[s][t]  = sd[t] - rh[t];
            rcnt[s][t] = rh[t];
        }
        __syncthreads();

        if (t < cnt) {
            const int rl = (ev0.y >> 16) & 63;
            buf[s * CAPF + rex[s][rl] + atomicAdd(&rc[rl], 1)] =
                make_uint2(ev0.x, ev0.y & 0xFFFFu);
        }
        if (t + 512 < cnt) {
            const int rl = (ev1.y >> 16) & 63;
            buf[s * CAPF + rex[s][rl] + atomicAdd(&rc[rl], 1)] =
                make_uint2(ev1.x, ev1.y & 0xFFFFu);
        }
        if (t + 1024 < cnt) {
            const int rl = (ev2.y >> 16) & 63;
            buf[s * CAPF + rex[s][rl] + atomicAdd(&rc[rl], 1)] =
                make_uint2(ev2.x, ev2.y & 0xFFFFu);
        }
        __syncthreads();
    }

    // ---- gather: 8 waves x 8 rows, both supports accumulated per row ----
    const int lane = t & 63;
    const int q    = lane >> 4;
    const int fl   = lane & 15;
    const int wv   = t >> 6;

    for (int ri = 0; ri < 8; ++ri) {
        const int rloc = wv * 8 + ri;
        const int row  = bk * 64 + rloc;

        float a[8];
#pragma unroll
        for (int k = 0; k < 8; ++k) a[k] = 0.f;

#pragma unroll
        for (int s = 0; s < N_SUP; ++s) {
            const int start = rex[s][rloc];
            const int cnt   = rcnt[s][rloc];
            const uint2* eb = buf + s * CAPF + start;
            const uint4* psup = pre_q + (size_t)s * N_NODES * 16 + fl;

            for (int e0 = 0; e0 < cnt; e0 += 64) {
                const int m = min(64, cnt - e0);
                int   c = 0;
                float v = 0.f;
                if (lane < m) {
                    const uint2 ed = eb[e0 + lane];
                    v = __uint_as_float(ed.x);
                    c = (int)ed.y;
                }
                const int steps = (m + 3) >> 2;

                auto step = [&](int jj) {
                    const int   idx = (jj < m) ? jj : 0;
                    float vj = __shfl(v, idx);
                    const int cj = __shfl(c, idx);
                    if (jj >= m) vj = 0.f;
                    const uint4 p = psup[(size_t)cj * 16];
                    a[0] += vj * __uint_as_float(p.x << 16);
                    a[1] += vj * __uint_as_float(p.x & 0xffff0000u);
                    a[2] += vj * __uint_as_float(p.y << 16);
                    a[3] += vj * __uint_as_float(p.y & 0xffff0000u);
                    a[4] += vj * __uint_as_float(p.z << 16);
                    a[5] += vj * __uint_as_float(p.z & 0xffff0000u);
                    a[6] += vj * __uint_as_float(p.w << 16);
                    a[7] += vj * __uint_as_float(p.w & 0xffff0000u);
                };
                int jj = 0;
                for (; jj + 1 < steps; jj += 2) {
                    step(jj * 4 + q);
                    step(jj * 4 + 4 + q);
                }
                if (jj < steps) step(jj * 4 + q);
            }
        }

#pragma unroll
        for (int k = 0; k < 8; ++k) {
            a[k] += __shfl_xor(a[k], 16);
            a[k] += __shfl_xor(a[k], 32);
        }

        if (lane < 16 && row < N_NODES) {
            const float4 b0 = *(const float4*)(bias + fl * 8);
            const float4 b1 = *(const float4*)(bias + fl * 8 + 4);
            float4 o0, o1;
            o0.x = fmaxf(a[0] + b0.x, 0.f);
            o0.y = fmaxf(a[1] + b0.y, 0.f);
            o0.z = fmaxf(a[2] + b0.z, 0.f);
            o0.w = fmaxf(a[3] + b0.w, 0.f);
            o1.x = fmaxf(a[4] + b1.x, 0.f);
            o1.y = fmaxf(a[5] + b1.y, 0.f);
            o1.z = fmaxf(a[6] + b1.z, 0.f);
            o1.w = fmaxf(a[7] + b1.w, 0.f);
            float* dst = out + (size_t)row * D_OUT + fl * 8;
            *(float4*)(dst)     = o0;
            *(float4*)(dst + 4) = o1;
        }
    }
}

extern "C" void kernel_launch(void* const* d_in, const int* in_sizes, int n_in,
                              void* d_out, int out_size, void* d_ws, size_t ws_size,
                              hipStream_t stream) {
    const float* x        = (const float*)d_in[0];
    const float* kernels  = (const float*)d_in[1];
    const float* bias     = (const float*)d_in[2];
    const float* adj_vals = (const float*)d_in[3];
    const int*   adj_rows = (const int*)d_in[4];
    const int*   adj_cols = (const int*)d_in[5];
    float* out = (float*)d_out;

    // ---- workspace layout ----
    char* ws = (char*)d_ws;
    size_t off = 0;
    auto alloc = [&](size_t bytes) {
        char* p = ws + off;
        off += (bytes + 255) & ~(size_t)255;
        return p;
    };
    __bf16* pre    = (__bf16*)alloc(sizeof(__bf16) * N_SUP * N_NODES * D_OUT); // 25.6 MB
    uint2*  coarse = (uint2*) alloc(sizeof(uint2)  * NB * CAPF);               // 16.0 MB
    int*    gcursor = (int*)alloc(sizeof(int) * NB);                           // 6.3 KB

    // K1: GEMM (inline W-cvt, dbuf LDS, 2-deep prefetch) + gcursor zero
    gemm_bf16_v3<<<GGRID, 512, 0, stream>>>(x, kernels, pre, gcursor);

    // K2: coarse scatter into 64-row buckets
    scatter_coarse<<<512, 512, 0, stream>>>(adj_vals, adj_rows, adj_cols,
                                            gcursor, coarse);

    // K3: fine sort + gather + bias + ReLU (merged)
    fine_gather<<<NB_S, 512, 0, stream>>>(coarse, gcursor, (const uint4*)pre,
                                          bias, out);
}